// Round 5
// baseline (2265.206 us; speedup 1.0000x reference)
//
#include <hip/hip_runtime.h>
#include <hip/hip_bf16.h>
#include <math.h>

typedef __hip_bfloat16 bf16;
typedef __bf16 bf16x8 __attribute__((ext_vector_type(8)));
typedef float f32x4 __attribute__((ext_vector_type(4)));

#define L_   2
#define D_   1024
#define NH_  16
#define DH_  64
#define FF_  4096
#define B_   64
#define SQ_  128
#define SK_  512
#define MTOK (B_ * SQ_)   // 8192 query tokens
#define MCTX (B_ * SK_)   // 32768 context tokens

// async global->LDS, 16B per lane; LDS dest is wave-uniform base + lane*16
#define GLDS16(gp, lp) __builtin_amdgcn_global_load_lds( \
    (__attribute__((address_space(1))) void*)(gp),        \
    (__attribute__((address_space(3))) void*)(lp), 16, 0, 0)

// ---------------- transpose + f32->bf16 (+scale): in (R x C) f32 -> out (C x R) bf16 ------
__global__ __launch_bounds__(256) void transpose_kernel(
    const float* __restrict__ in, bf16* __restrict__ out, int R, int C, float scale)
{
  __shared__ bf16 t[32][33];
  const int bx = blockIdx.x * 32;  // col tile origin
  const int by = blockIdx.y * 32;  // row tile origin
  const int tid = threadIdx.x;
#pragma unroll
  for (int e = 0; e < 4; ++e) {
    int i = tid + e * 256, rr = i >> 5, cc = i & 31;
    t[rr][cc] = __float2bfloat16(scale * in[(size_t)(by + rr) * C + bx + cc]);
  }
  __syncthreads();
#pragma unroll
  for (int e = 0; e < 4; ++e) {
    int i = tid + e * 256, rr = i >> 5, cc = i & 31;
    out[(size_t)(bx + rr) * R + by + cc] = t[cc][rr];
  }
}

// ---------------- f32 -> bf16 bulk convert: 8 elements per thread ----------------
__global__ __launch_bounds__(256) void convert_kernel(
    const float* __restrict__ in, bf16* __restrict__ out)
{
  const size_t i = ((size_t)blockIdx.x * 256 + threadIdx.x) * 8;
  const float4 f0 = *(const float4*)(in + i);
  const float4 f1 = *(const float4*)(in + i + 4);
  bf16x8 v = { (__bf16)f0.x, (__bf16)f0.y, (__bf16)f0.z, (__bf16)f0.w,
               (__bf16)f1.x, (__bf16)f1.y, (__bf16)f1.z, (__bf16)f1.w };
  *(bf16x8*)(out + i) = v;
}

// ---------------- rmsnorm: f32 in, f32 weight, bf16 out; one block per row (D=1024) -------
__global__ __launch_bounds__(256) void rmsnorm_kernel(
    const float* __restrict__ x, const float* __restrict__ w, bf16* __restrict__ out)
{
  const int row = blockIdx.x, tid = threadIdx.x;
  const float4 v = ((const float4*)(x + (size_t)row * D_))[tid];
  float ss = v.x * v.x + v.y * v.y + v.z * v.z + v.w * v.w;
#pragma unroll
  for (int m = 1; m < 64; m <<= 1) ss += __shfl_xor(ss, m, 64);
  __shared__ float red[4];
  if ((tid & 63) == 0) red[tid >> 6] = ss;
  __syncthreads();
  const float tot = red[0] + red[1] + red[2] + red[3];
  const float inv = 1.0f / fmaxf(sqrtf(tot * (1.0f / D_)), 1e-8f);
  const float4 wv = ((const float4*)w)[tid];
  bf16* o = out + (size_t)row * D_ + tid * 4;
  o[0] = __float2bfloat16(v.x * inv * wv.x);
  o[1] = __float2bfloat16(v.y * inv * wv.y);
  o[2] = __float2bfloat16(v.z * inv * wv.z);
  o[3] = __float2bfloat16(v.w * inv * wv.w);
}

// ---------------- RoPE in-place: rows x (ld) bf16, rotate dims [0,32) of each head --------
__global__ __launch_bounds__(256) void rope_kernel(bf16* __restrict__ t, int posmask, int ld)
{
  const int row = blockIdx.x, tid = threadIdx.x;
  const int h = tid >> 4, d = tid & 15;
  const float pos = (float)(row & posmask);
  const float inv_freq = expf(-(float)d * 0.5756462732485115f);  // 10000^(-d/16)
  const float f = pos * inv_freq;
  const float c = cosf(f), s = sinf(f);
  const size_t base = (size_t)row * ld + h * DH_ + d;
  const float a = __bfloat162float(t[base]);
  const float b = __bfloat162float(t[base + 16]);
  t[base]      = __float2bfloat16(a * c - b * s);
  t[base + 16] = __float2bfloat16(b * c + a * s);
}

// ---------------- GEMM 128x128 (proven): used for N=1024 shapes -------------------
// MODE 0: bf16 out = acc + bias          MODE 1: bf16 out = gelu(acc + bias)
// MODE 2: f32 out = acc + bias + resid   MODE 3: f32 out = acc + bias
template <int MODE, int AF32>
__global__ __launch_bounds__(256) void gemm_bt_kernel(
    const void* __restrict__ Ap, const bf16* __restrict__ Bt,
    void* Cout, const float* __restrict__ bias, const float* resid,
    int M, int N, int K)
{
  __shared__ __align__(16) char smem[16384];  // As(8K) + Bs(8K) | epilogue bounce (8.7K)
  bf16* As = (bf16*)smem;            // [128][32]
  bf16* Bs = (bf16*)(smem + 8192);   // [128][32]
  const int tid = threadIdx.x;
  const int wave = tid >> 6, lane = tid & 63;
  const int wm = wave >> 1, wn = wave & 1;

  const int npidn = gridDim.x, npidm = gridDim.y;
  const int pid = blockIdx.y * npidn + blockIdx.x;
  const int group_sz = 8 * npidn;
  const int gid = pid / group_sz;
  const int first_m = gid * 8;
  const int gsm = min(npidm - first_m, 8);
  const int pid_m = first_m + (pid % gsm);
  const int pid_n = (pid % group_sz) / gsm;
  const int m0 = pid_m * 128, n0 = pid_n * 128;

  const int r = lane & 15, qd = lane >> 4;
  const int srow = lane >> 2, scol = (lane & 3) * 8;

  f32x4 acc[4][4] = {};

  for (int k0 = 0; k0 < K; k0 += 32) {
#pragma unroll
    for (int t = 0; t < 2; ++t) {
      const int g = wave * 2 + t;
      if (AF32) {
        const float* A32 = (const float*)Ap;
        const float4 f0 = *(const float4*)(A32 + (size_t)(m0 + g * 16 + srow) * K + k0 + scol);
        const float4 f1 = *(const float4*)(A32 + (size_t)(m0 + g * 16 + srow) * K + k0 + scol + 4);
        bf16x8 v = { (__bf16)f0.x, (__bf16)f0.y, (__bf16)f0.z, (__bf16)f0.w,
                     (__bf16)f1.x, (__bf16)f1.y, (__bf16)f1.z, (__bf16)f1.w };
        *(bf16x8*)&As[g * 512 + lane * 8] = v;
      } else {
        const bf16* A16 = (const bf16*)Ap;
        GLDS16(A16 + (size_t)(m0 + g * 16 + srow) * K + k0 + scol, &As[g * 512]);
      }
      GLDS16(Bt + (size_t)(n0 + g * 16 + srow) * K + k0 + scol, &Bs[g * 512]);
    }
    __syncthreads();
    bf16x8 af[4], bfr[4];
#pragma unroll
    for (int i = 0; i < 4; ++i)
      af[i] = *(const bf16x8*)&As[(wm * 64 + i * 16 + r) * 32 + qd * 8];
#pragma unroll
    for (int j = 0; j < 4; ++j)
      bfr[j] = *(const bf16x8*)&Bs[(wn * 64 + j * 16 + r) * 32 + qd * 8];
#pragma unroll
    for (int i = 0; i < 4; ++i)
#pragma unroll
      for (int j = 0; j < 4; ++j)
        acc[i][j] = __builtin_amdgcn_mfma_f32_16x16x32_bf16(af[i], bfr[j], acc[i][j], 0, 0, 0);
    __syncthreads();
  }

  if (MODE == 0 || MODE == 1) {
    bf16* Wb = (bf16*)smem + wave * (16 * 68);
    const int rw = lane >> 2, c0 = (lane & 3) * 8;
#pragma unroll
    for (int i = 0; i < 4; ++i) {
#pragma unroll
      for (int j = 0; j < 4; ++j) {
        const int col = wn * 64 + j * 16 + r;
        const float bv = bias ? bias[n0 + col] : 0.f;
#pragma unroll
        for (int rr = 0; rr < 4; ++rr) {
          float v = acc[i][j][rr] + bv;
          if (MODE == 1) v = 0.5f * v * (1.f + erff(v * 0.70710678118654752f));
          Wb[(qd * 4 + rr) * 68 + j * 16 + r] = __float2bfloat16(v);
        }
      }
      asm volatile("s_waitcnt lgkmcnt(0)" ::: "memory");
      const int row_g = m0 + wm * 64 + i * 16 + rw;
      const bf16x8 v0 = *(const bf16x8*)&Wb[rw * 68 + c0];
      const bf16x8 v1 = *(const bf16x8*)&Wb[rw * 68 + 32 + c0];
      *(bf16x8*)((bf16*)Cout + (size_t)row_g * N + n0 + wn * 64 + c0)      = v0;
      *(bf16x8*)((bf16*)Cout + (size_t)row_g * N + n0 + wn * 64 + 32 + c0) = v1;
      asm volatile("" ::: "memory");
    }
  } else {
#pragma unroll
    for (int i = 0; i < 4; ++i) {
      const int row = m0 + wm * 64 + i * 16 + qd * 4;
#pragma unroll
      for (int j = 0; j < 4; ++j) {
        const int col = n0 + wn * 64 + j * 16 + r;
        const float bv = bias ? bias[col] : 0.f;
#pragma unroll
        for (int rr = 0; rr < 4; ++rr) {
          float v = acc[i][j][rr] + bv;
          const size_t idx = (size_t)(row + rr) * N + col;
          if (MODE == 2) ((float*)Cout)[idx] = v + resid[idx];
          else           ((float*)Cout)[idx] = v;
        }
      }
    }
  }
}

// ============ GEMM 256x256, 8-wave (2x4), BK=64, 8-phase counted-vmcnt pipeline ============
// T3+T4 port with K-half slab staging (uniform waits). LDS 128 KB:
//   A[buf][kk]: 256 rows x 32 cols bf16 (64B rows), B[buf][kk] same with Bt n-rows.
// XOR swizzle: 16B-slot = q ^ ((row>>1)&3)  (2-way max on ds_read_b128; staging pre-swizzles
// the GLOBAL source column, LDS dest linear — rule 21).
// Stage stagger: T.ph1->L(T+1.Ak1), ph2->L(T+1.Bk1), ph3->L(T+2.Ak0), ph4->L(T+2.Bk0);
// waits vmcnt(8) at end of even phases (4 slabs / 8 instrs in flight). Last 2 tiles peeled
// with exact drains 8->4->0. Requires M%256==0, N%256==0, K%64==0, K>=192.
#define VM8 asm volatile("s_waitcnt vmcnt(8)" ::: "memory")
#define VM4 asm volatile("s_waitcnt vmcnt(4)" ::: "memory")
#define VM0 asm volatile("s_waitcnt vmcnt(0)" ::: "memory")
#define NOPST (void)0

#define PHASE256(BUF, KK, H, STAGE_STMT, WAIT_STMT) {                                   \
  bf16x8 af[4], bv[4];                                                                  \
  const int ab_ = ((BUF) * 2 + (KK)) * 8192;                                            \
  const int bb_ = 32768 + ((BUF) * 2 + (KK)) * 8192;                                    \
  _Pragma("unroll") for (int i2 = 0; i2 < 4; ++i2) {                                    \
    const int rl = wm * 128 + (H) * 64 + i2 * 16 + r;                                   \
    af[i2] = *(const bf16x8*)&sm[ab_ + rl * 32 + ((qd ^ ((rl >> 1) & 3)) << 3)];        \
  }                                                                                     \
  _Pragma("unroll") for (int j = 0; j < 4; ++j) {                                       \
    const int rl = wn * 64 + j * 16 + r;                                                \
    bv[j] = *(const bf16x8*)&sm[bb_ + rl * 32 + ((qd ^ ((rl >> 1) & 3)) << 3)];         \
  }                                                                                     \
  STAGE_STMT;                                                                           \
  __builtin_amdgcn_s_barrier();                                                         \
  asm volatile("s_waitcnt lgkmcnt(0)" ::: "memory");                                    \
  __builtin_amdgcn_sched_barrier(0);                                                    \
  __builtin_amdgcn_s_setprio(1);                                                        \
  _Pragma("unroll") for (int i2 = 0; i2 < 4; ++i2)                                      \
    _Pragma("unroll") for (int j = 0; j < 4; ++j)                                       \
      acc[(H) * 4 + i2][j] =                                                            \
          __builtin_amdgcn_mfma_f32_16x16x32_bf16(af[i2], bv[j], acc[(H) * 4 + i2][j],  \
                                                  0, 0, 0);                             \
  __builtin_amdgcn_s_setprio(0);                                                        \
  WAIT_STMT;                                                                            \
  __builtin_amdgcn_s_barrier();                                                         \
  __builtin_amdgcn_sched_barrier(0);                                                    \
}

template <int MODE>  // 0: bf16 (+bias opt); 1: bf16 gelu(+bias); 2: f32 + bias + resid
__global__ __launch_bounds__(512, 2) void gemm256_kernel(
    const bf16* __restrict__ A, const bf16* __restrict__ Bt,
    void* Cout, const float* __restrict__ bias, const float* __restrict__ resid,
    int M, int N, int K)
{
  __shared__ __align__(16) bf16 sm[65536];  // 128 KB
  const int tid = threadIdx.x;
  const int wave = tid >> 6, lane = tid & 63;
  const int wm = wave >> 2, wn = wave & 3;  // 2 x 4 wave grid, per-wave C = 128x64
  const int r = lane & 15, qd = lane >> 4;

  const int nbn = N >> 8;
  const int nwg = (M >> 8) * nbn;
  int pid = blockIdx.x;
  if ((nwg & 7) == 0) pid = (pid & 7) * (nwg >> 3) + (pid >> 3);  // bijective XCD chunking
  const int m0 = (pid / nbn) << 8, n0 = (pid % nbn) << 8;

  const int srow = lane >> 2, ssl = lane & 3;
  // stage one K-half slab (256 rows x 32 cols) into LDS at element offset `slab`
  auto stage = [&](const bf16* src, int row0, int kbase, int slab) {
    const int ra = wave * 32 + srow;
    GLDS16(src + (size_t)(row0 + ra) * K + kbase + ((ssl ^ ((ra >> 1) & 3)) << 3),
           &sm[slab + wave * 1024]);
    const int rb = ra + 16;
    GLDS16(src + (size_t)(row0 + rb) * K + kbase + ((ssl ^ ((rb >> 1) & 3)) << 3),
           &sm[slab + wave * 1024 + 512]);
  };
  auto AOF = [](int buf, int kk) { return (buf * 2 + kk) * 8192; };
  auto BOF = [](int buf, int kk) { return 32768 + (buf * 2 + kk) * 8192; };

  f32x4 acc[8][4] = {};

  // ---- prologue: tile0 all 4 slabs + tile1 k0 slabs ----
  stage(A,  m0, 0,  AOF(0, 0));
  stage(Bt, n0, 0,  BOF(0, 0));
  stage(A,  m0, 32, AOF(0, 1));
  stage(Bt, n0, 32, BOF(0, 1));
  stage(A,  m0, 64, AOF(1, 0));
  stage(Bt, n0, 64, BOF(1, 0));
  VM8;  // oldest 4 instrs (tile0 Ak0,Bk0) complete
  __builtin_amdgcn_s_barrier();
  __builtin_amdgcn_sched_barrier(0);

  const int NT = K >> 6;
  int buf = 0;
  for (int t = 0; t + 2 < NT; ++t) {
    const int o = buf;
    PHASE256(o, 0, 0, stage(A,  m0, (t + 1) * 64 + 32, AOF(o ^ 1, 1)), NOPST);
    PHASE256(o, 0, 1, stage(Bt, n0, (t + 1) * 64 + 32, BOF(o ^ 1, 1)), VM8);
    PHASE256(o, 1, 0, stage(A,  m0, (t + 2) * 64,      AOF(o, 0)),     NOPST);
    PHASE256(o, 1, 1, stage(Bt, n0, (t + 2) * 64,      BOF(o, 0)),     VM8);
    buf ^= 1;
  }
  {  // tile NT-2
    const int o = buf, t = NT - 2;
    PHASE256(o, 0, 0, stage(A,  m0, (t + 1) * 64 + 32, AOF(o ^ 1, 1)), NOPST);
    PHASE256(o, 0, 1, stage(Bt, n0, (t + 1) * 64 + 32, BOF(o ^ 1, 1)), VM8);
    PHASE256(o, 1, 0, NOPST, NOPST);
    PHASE256(o, 1, 1, NOPST, VM4);
    buf ^= 1;
  }
  {  // tile NT-1 (drain)
    const int o = buf;
    PHASE256(o, 0, 0, NOPST, NOPST);
    PHASE256(o, 0, 1, NOPST, VM0);
    PHASE256(o, 1, 0, NOPST, NOPST);
    PHASE256(o, 1, 1, NOPST, NOPST);
  }

  // ---- epilogue ----
  if (MODE <= 1) {
    bf16* Wb = sm + wave * (16 * 68);  // per-wave bounce; all LDS reads retired by last barrier
    const int rw = lane >> 2, c0 = (lane & 3) * 8;
#pragma unroll
    for (int i = 0; i < 8; ++i) {
#pragma unroll
      for (int j = 0; j < 4; ++j) {
        const int col = wn * 64 + j * 16 + r;
        const float bvs = bias ? bias[n0 + col] : 0.f;
#pragma unroll
        for (int rr = 0; rr < 4; ++rr) {
          float v = acc[i][j][rr] + bvs;
          if (MODE == 1) v = 0.5f * v * (1.f + erff(v * 0.70710678118654752f));
          Wb[(qd * 4 + rr) * 68 + j * 16 + r] = __float2bfloat16(v);
        }
      }
      asm volatile("s_waitcnt lgkmcnt(0)" ::: "memory");
      const int row_g = m0 + wm * 128 + i * 16 + rw;
      const bf16x8 v0 = *(const bf16x8*)&Wb[rw * 68 + c0];
      const bf16x8 v1 = *(const bf16x8*)&Wb[rw * 68 + 32 + c0];
      *(bf16x8*)((bf16*)Cout + (size_t)row_g * N + n0 + wn * 64 + c0)      = v0;
      *(bf16x8*)((bf16*)Cout + (size_t)row_g * N + n0 + wn * 64 + 32 + c0) = v1;
      asm volatile("" ::: "memory");
    }
  } else {
#pragma unroll
    for (int i = 0; i < 8; ++i) {
      const int row = m0 + wm * 128 + i * 16 + qd * 4;
#pragma unroll
      for (int j = 0; j < 4; ++j) {
        const int col = n0 + wn * 64 + j * 16 + r;
        const float bv = bias ? bias[col] : 0.f;
#pragma unroll
        for (int rr = 0; rr < 4; ++rr) {
          const size_t idx = (size_t)(row + rr) * N + col;
          ((float*)Cout)[idx] = acc[i][j][rr] + bv + (resid ? resid[idx] : 0.f);
        }
      }
    }
  }
}

// ---------------- fused attention (unchanged, proven) ----------------
__global__ __launch_bounds__(256) void attn_kernel(
    const bf16* __restrict__ Q, const bf16* __restrict__ Kg,
    const bf16* __restrict__ Vg, bf16* __restrict__ Out,
    int nk, int ldq, int ldkv)
{
  __shared__ __align__(16) bf16 Qs[128 * 64];
  __shared__ __align__(16) bf16 Ks[64 * 64];
  __shared__ __align__(16) bf16 Vt[64 * 64];
  __shared__ __align__(16) bf16 Ps[128 * 64];
  const int tid = threadIdx.x;
  const int wave = tid >> 6, lane = tid & 63;
  const int b = blockIdx.x >> 4, h = blockIdx.x & 15;
  const int r = lane & 15, qd = lane >> 4;
  const int srow = lane >> 3;
  const int scol = ((lane & 7) ^ srow) * 8;

#pragma unroll
  for (int t = 0; t < 4; ++t) {
    const int g = wave * 4 + t;
    GLDS16(Q + (size_t)(b * SQ_ + g * 8 + srow) * ldq + h * DH_ + scol, &Qs[g * 512]);
  }

  float mrow[2][4], lrow[2][4];
  f32x4 Oacc[2][4] = {};
#pragma unroll
  for (int i = 0; i < 2; ++i)
#pragma unroll
    for (int rr = 0; rr < 4; ++rr) { mrow[i][rr] = -1e30f; lrow[i][rr] = 0.f; }

  for (int kt = 0; kt < nk; kt += 64) {
#pragma unroll
    for (int t = 0; t < 2; ++t) {
      const int g = wave * 2 + t;
      GLDS16(Kg + (size_t)(b * nk + kt + g * 8 + srow) * ldkv + h * DH_ + scol, &Ks[g * 512]);
    }
#pragma unroll
    for (int c = 0; c < 2; ++c) {
      const int chunk = c * 256 + tid;
      const int key = chunk >> 3, d0 = (chunk & 7) * 8;
      const uint4 pv = *(const uint4*)(Vg + (size_t)(b * nk + kt + key) * ldkv + h * DH_ + d0);
      const unsigned short* pu = (const unsigned short*)&pv;
      const int s0 = key >> 3, k7 = key & 7;
#pragma unroll
      for (int t2 = 0; t2 < 8; ++t2) {
        const int row = d0 + t2;
        ((unsigned short*)Vt)[row * 64 + ((s0 ^ (row & 7)) << 3) + k7] = pu[t2];
      }
    }
    __syncthreads();

    f32x4 S[2][4] = {};
#pragma unroll
    for (int ks = 0; ks < 2; ++ks) {
      const int sl = ((ks * 4 + qd) ^ (r & 7)) * 8;
      bf16x8 aq[2], bk[4];
#pragma unroll
      for (int i = 0; i < 2; ++i)
        aq[i] = *(const bf16x8*)&Qs[(wave * 32 + i * 16 + r) * 64 + sl];
#pragma unroll
      for (int j = 0; j < 4; ++j)
        bk[j] = *(const bf16x8*)&Ks[(j * 16 + r) * 64 + sl];
#pragma unroll
      for (int i = 0; i < 2; ++i)
#pragma unroll
        for (int j = 0; j < 4; ++j)
          S[i][j] = __builtin_amdgcn_mfma_f32_16x16x32_bf16(aq[i], bk[j], S[i][j], 0, 0, 0);
    }

#pragma unroll
    for (int i = 0; i < 2; ++i) {
#pragma unroll
      for (int rr = 0; rr < 4; ++rr) {
        float mx = fmaxf(fmaxf(S[i][0][rr], S[i][1][rr]), fmaxf(S[i][2][rr], S[i][3][rr]));
#pragma unroll
        for (int mm = 1; mm < 16; mm <<= 1) mx = fmaxf(mx, __shfl_xor(mx, mm, 64));
        const float mnew = fmaxf(mrow[i][rr], mx);
        const float alpha = __expf(mrow[i][rr] - mnew);
        mrow[i][rr] = mnew;
        const int prow = wave * 32 + i * 16 + qd * 4 + rr;
        const int pr7 = prow & 7;
        float rs = 0.f;
#pragma unroll
        for (int j = 0; j < 4; ++j) {
          const float p = __expf(S[i][j][rr] - mnew);
          rs += p;
          Ps[prow * 64 + (((j * 2 + (r >> 3)) ^ pr7) << 3) + (r & 7)] = __float2bfloat16(p);
        }
#pragma unroll
        for (int mm = 1; mm < 16; mm <<= 1) rs += __shfl_xor(rs, mm, 64);
        lrow[i][rr] = lrow[i][rr] * alpha + rs;
#pragma unroll
        for (int jd = 0; jd < 4; ++jd) Oacc[i][jd][rr] *= alpha;
      }
    }
    __syncthreads();

#pragma unroll
    for (int ks = 0; ks < 2; ++ks) {
      const int sl = ((ks * 4 + qd) ^ (r & 7)) * 8;
      bf16x8 ap[2], bv[4];
#pragma unroll
      for (int i = 0; i < 2; ++i)
        ap[i] = *(const bf16x8*)&Ps[(wave * 32 + i * 16 + r) * 64 + sl];
#pragma unroll
      for (int jd = 0; jd < 4; ++jd)
        bv[jd] = *(const bf16x8*)&Vt[(jd * 16 + r) * 64 + sl];
#pragma unroll
      for (int i = 0; i < 2; ++i)
#pragma unroll
        for (int jd = 0; jd < 4; ++jd)
          Oacc[i][jd] = __builtin_amdgcn_mfma_f32_16x16x32_bf16(ap[i], bv[jd], Oacc[i][jd], 0, 0, 0);
    }
    __syncthreads();
  }

#pragma unroll
  for (int i = 0; i < 2; ++i) {
    const int rowl = wave * 32 + i * 16 + qd * 4;
#pragma unroll
    for (int jd = 0; jd < 4; ++jd) {
      const int col = h * DH_ + jd * 16 + r;
#pragma unroll
      for (int rr = 0; rr < 4; ++rr)
        Out[(size_t)(b * SQ_ + rowl + rr) * D_ + col] =
            __float2bfloat16(Oacc[i][jd][rr] / lrow[i][rr]);
    }
  }
}

extern "C" void kernel_launch(void* const* d_in, const int* in_sizes, int n_in,
                              void* d_out, int out_size, void* d_ws, size_t ws_size,
                              hipStream_t stream)
{
  (void)in_sizes; (void)n_in; (void)out_size;
  const float* x_in         = (const float*)d_in[0];
  const float* ctx          = (const float*)d_in[1];
  const float* attn_norm_w  = (const float*)d_in[3];
  const float* Wq           = (const float*)d_in[4];
  const float* Wk           = (const float*)d_in[5];
  const float* Wv           = (const float*)d_in[6];
  const float* Wo           = (const float*)d_in[7];
  const float* bo           = (const float*)d_in[8];
  const float* cross_norm_w = (const float*)d_in[9];
  const float* cWq          = (const float*)d_in[10];
  const float* cWk          = (const float*)d_in[11];
  const float* cWv          = (const float*)d_in[12];
  const float* cWo          = (const float*)d_in[13];
  const float* cbo          = (const float*)d_in[14];
  const float* ff_norm_w    = (const float*)d_in[15];
  const float* ff_w1        = (const float*)d_in[16];
  const float* ff_b1        = (const float*)d_in[17];
  const float* ff_w2        = (const float*)d_in[18];
  const float* ff_b2        = (const float*)d_in[19];
  const float* norm_out_w   = (const float*)d_in[20];
  const float* proj_w       = (const float*)d_in[21];
  const float* proj_b       = (const float*)d_in[22];

  char* ws = (char*)d_ws;
  size_t off = 0;
  auto carve = [&](size_t bytes) -> void* {
    void* p = ws + off;
    off += (bytes + 255) & ~(size_t)255;
    return p;
  };
  const size_t DD = (size_t)D_ * D_;
  bf16*  Wt  = (bf16*)carve((size_t)FF_ * D_ * 2);
  float* xf  = (float*)carve((size_t)MTOK * D_ * 4);
  bf16*  hb  = (bf16*)carve((size_t)MTOK * D_ * 2);
  bf16*  ao  = hb;
  char*  big = (char*)carve((size_t)144 * 1024 * 1024);
  bf16*  qkvb = (bf16*)big;
  bf16*  qb   = (bf16*)big;
  bf16*  kvb  = (bf16*)(big + (size_t)16 * 1024 * 1024);
  bf16*  gbuf = (bf16*)big;
  bf16*  ctxb = (bf16*)carve((size_t)MCTX * D_ * 2);
  const bool ctx16 = (ws_size >= off);

  auto T = [&](const float* src, bf16* dst, int R, int C, float scale = 1.0f) {
    transpose_kernel<<<dim3(C / 32, R / 32), 256, 0, stream>>>(src, dst, R, C, scale);
  };
  // 128^2 kernel wrappers (N=1024 shapes)
  auto G0 = [&](const bf16* A, bf16* C, int M, int N, int K) {
    gemm_bt_kernel<0, 0><<<dim3(N / 128, M / 128), 256, 0, stream>>>(
        (const void*)A, Wt, (void*)C, nullptr, nullptr, M, N, K);
  };
  auto G0f = [&](const float* A, bf16* C, int M, int N, int K) {
    gemm_bt_kernel<0, 1><<<dim3(N / 128, M / 128), 256, 0, stream>>>(
        (const void*)A, Wt, (void*)C, nullptr, nullptr, M, N, K);
  };
  auto G2 = [&](const bf16* A, const float* bias, const float* resid, int M, int N, int K) {
    gemm_bt_kernel<2, 0><<<dim3(N / 128, M / 128), 256, 0, stream>>>(
        (const void*)A, Wt, (void*)xf, bias, resid, M, N, K);
  };
  auto G3 = [&](const bf16* A, float* C, const float* bias, int M, int N, int K) {
    gemm_bt_kernel<3, 0><<<dim3(N / 128, M / 128), 256, 0, stream>>>(
        (const void*)A, Wt, (void*)C, bias, nullptr, M, N, K);
  };
  // 256^2 8-phase kernel wrappers (M%256==0, N%256==0, K%64==0, K>=192)
  auto H0 = [&](const bf16* A, bf16* C, int M, int N, int K) {
    gemm256_kernel<0><<<dim3((M / 256) * (N / 256)), 512, 0, stream>>>(
        A, Wt, (void*)C, nullptr, nullptr, M, N, K);
  };
  auto H1 = [&](const bf16* A, bf16* C, const float* bias, int M, int N, int K) {
    gemm256_kernel<1><<<dim3((M / 256) * (N / 256)), 512, 0, stream>>>(
        A, Wt, (void*)C, bias, nullptr, M, N, K);
  };
  auto H2 = [&](const bf16* A, const float* bias, const float* resid, int M, int N, int K) {
    gemm256_kernel<2><<<dim3((M / 256) * (N / 256)), 512, 0, stream>>>(
        A, Wt, (void*)xf, bias, resid, M, N, K);
  };

  if (ctx16)
    convert_kernel<<<(MCTX * D_) / (256 * 8), 256, 0, stream>>>(ctx, ctxb);

  for (int l = 0; l < L_; ++l) {
    const size_t o1 = (size_t)l * DD;
    const size_t o4 = (size_t)l * D_ * FF_;
    const float* res0 = (l == 0) ? x_in : xf;
    // ---- self-attention (fused QKV GEMM, N=3072; DH^-0.5 folded into Wq) ----
    rmsnorm_kernel<<<MTOK, 256, 0, stream>>>(res0, attn_norm_w + l * D_, hb);
    T(Wq + o1, Wt,          D_, D_, 0.125f);
    T(Wk + o1, Wt + DD,     D_, D_);
    T(Wv + o1, Wt + 2 * DD, D_, D_);
    H0(hb, qkvb, MTOK, 3 * D_, D_);
    rope_kernel<<<MTOK, 256, 0, stream>>>(qkvb,      SQ_ - 1, 3 * D_);
    rope_kernel<<<MTOK, 256, 0, stream>>>(qkvb + D_, SQ_ - 1, 3 * D_);
    attn_kernel<<<B_ * NH_, 256, 0, stream>>>(qkvb, qkvb + D_, qkvb + 2 * D_, ao,
                                              SQ_, 3 * D_, 3 * D_);
    T(Wo + o1, Wt, D_, D_);
    G2(ao, bo + l * D_, res0, MTOK, D_, D_);
    // ---- cross-attention (fused KV GEMM from bf16 context, N=2048) ----
    rmsnorm_kernel<<<MTOK, 256, 0, stream>>>(xf, cross_norm_w + l * D_, hb);
    T(cWq + o1, Wt, D_, D_, 0.125f);
    G0(hb, qb, MTOK, D_, D_);
    T(cWk + o1, Wt,      D_, D_);
    T(cWv + o1, Wt + DD, D_, D_);
    if (ctx16) H0(ctxb, kvb, MCTX, 2 * D_, D_);
    else       G0f(ctx, kvb, MCTX, 2 * D_, D_);
    rope_kernel<<<MTOK, 256, 0, stream>>>(qb,  SQ_ - 1, D_);
    rope_kernel<<<MCTX, 256, 0, stream>>>(kvb, SK_ - 1, 2 * D_);
    attn_kernel<<<B_ * NH_, 256, 0, stream>>>(qb, kvb, kvb + D_, ao, SK_, D_, 2 * D_);
    T(cWo + o1, Wt, D_, D_);
    G2(ao, cbo + l * D_, xf, MTOK, D_, D_);
    // ---- FFN ----
    rmsnorm_kernel<<<MTOK, 256, 0, stream>>>(xf, ff_norm_w + l * D_, hb);
    T(ff_w1 + o4, Wt, D_, FF_);
    H1(hb, gbuf, ff_b1 + l * FF_, MTOK, FF_, D_);
    T(ff_w2 + o4, Wt, FF_, D_);
    H2(gbuf, ff_b2 + l * D_, xf, MTOK, D_, FF_);
  }
  rmsnorm_kernel<<<MTOK, 256, 0, stream>>>(xf, norm_out_w, hb);
  T(proj_w, Wt, D_, D_);
  G3(hb, (float*)d_out, proj_b, MTOK, D_, D_);
}

// Round 6
// 2019.793 us; speedup vs baseline: 1.1215x; 1.1215x over previous
//
#include <hip/hip_runtime.h>
#include <hip/hip_bf16.h>
#include <math.h>

typedef __hip_bfloat16 bf16;
typedef __bf16 bf16x8 __attribute__((ext_vector_type(8)));
typedef float f32x4 __attribute__((ext_vector_type(4)));

#define L_   2
#define D_   1024
#define NH_  16
#define DH_  64
#define FF_  4096
#define B_   64
#define SQ_  128
#define SK_  512
#define MTOK (B_ * SQ_)   // 8192 query tokens
#define MCTX (B_ * SK_)   // 32768 context tokens

// async global->LDS, 16B per lane; LDS dest is wave-uniform base + lane*16
#define GLDS16(gp, lp) __builtin_amdgcn_global_load_lds( \
    (__attribute__((address_space(1))) void*)(gp),        \
    (__attribute__((address_space(3))) void*)(lp), 16, 0, 0)

// ---------------- transpose + f32->bf16 (+scale): in (R x C) f32 -> out (C x R) bf16 ------
__global__ __launch_bounds__(256) void transpose_kernel(
    const float* __restrict__ in, bf16* __restrict__ out, int R, int C, float scale)
{
  __shared__ bf16 t[32][33];
  const int bx = blockIdx.x * 32;  // col tile origin
  const int by = blockIdx.y * 32;  // row tile origin
  const int tid = threadIdx.x;
#pragma unroll
  for (int e = 0; e < 4; ++e) {
    int i = tid + e * 256, rr = i >> 5, cc = i & 31;
    t[rr][cc] = __float2bfloat16(scale * in[(size_t)(by + rr) * C + bx + cc]);
  }
  __syncthreads();
#pragma unroll
  for (int e = 0; e < 4; ++e) {
    int i = tid + e * 256, rr = i >> 5, cc = i & 31;
    out[(size_t)(bx + rr) * R + by + cc] = t[cc][rr];
  }
}

// ---------------- f32 -> bf16 bulk convert: 8 elements per thread ----------------
__global__ __launch_bounds__(256) void convert_kernel(
    const float* __restrict__ in, bf16* __restrict__ out)
{
  const size_t i = ((size_t)blockIdx.x * 256 + threadIdx.x) * 8;
  const float4 f0 = *(const float4*)(in + i);
  const float4 f1 = *(const float4*)(in + i + 4);
  bf16x8 v = { (__bf16)f0.x, (__bf16)f0.y, (__bf16)f0.z, (__bf16)f0.w,
               (__bf16)f1.x, (__bf16)f1.y, (__bf16)f1.z, (__bf16)f1.w };
  *(bf16x8*)(out + i) = v;
}

// ---------------- rmsnorm: f32 in, f32 weight, bf16 out; one block per row (D=1024) -------
__global__ __launch_bounds__(256) void rmsnorm_kernel(
    const float* __restrict__ x, const float* __restrict__ w, bf16* __restrict__ out)
{
  const int row = blockIdx.x, tid = threadIdx.x;
  const float4 v = ((const float4*)(x + (size_t)row * D_))[tid];
  float ss = v.x * v.x + v.y * v.y + v.z * v.z + v.w * v.w;
#pragma unroll
  for (int m = 1; m < 64; m <<= 1) ss += __shfl_xor(ss, m, 64);
  __shared__ float red[4];
  if ((tid & 63) == 0) red[tid >> 6] = ss;
  __syncthreads();
  const float tot = red[0] + red[1] + red[2] + red[3];
  const float inv = 1.0f / fmaxf(sqrtf(tot * (1.0f / D_)), 1e-8f);
  const float4 wv = ((const float4*)w)[tid];
  bf16* o = out + (size_t)row * D_ + tid * 4;
  o[0] = __float2bfloat16(v.x * inv * wv.x);
  o[1] = __float2bfloat16(v.y * inv * wv.y);
  o[2] = __float2bfloat16(v.z * inv * wv.z);
  o[3] = __float2bfloat16(v.w * inv * wv.w);
}

// ---------------- RoPE in-place: rows x (ld) bf16, rotate dims [0,32) of each head --------
__global__ __launch_bounds__(256) void rope_kernel(bf16* __restrict__ t, int posmask, int ld)
{
  const int row = blockIdx.x, tid = threadIdx.x;
  const int h = tid >> 4, d = tid & 15;
  const float pos = (float)(row & posmask);
  const float inv_freq = expf(-(float)d * 0.5756462732485115f);  // 10000^(-d/16)
  const float f = pos * inv_freq;
  const float c = cosf(f), s = sinf(f);
  const size_t base = (size_t)row * ld + h * DH_ + d;
  const float a = __bfloat162float(t[base]);
  const float b = __bfloat162float(t[base + 16]);
  t[base]      = __float2bfloat16(a * c - b * s);
  t[base + 16] = __float2bfloat16(b * c + a * s);
}

// ---------------- GEMM 128x128 (proven): used for M=8192 / N=1024 shapes -------------------
// MODE 0: bf16 out = acc + bias          MODE 1: bf16 out = gelu(acc + bias)
// MODE 2: f32 out = acc + bias + resid   MODE 3: f32 out = acc + bias
template <int MODE, int AF32>
__global__ __launch_bounds__(256) void gemm_bt_kernel(
    const void* __restrict__ Ap, const bf16* __restrict__ Bt,
    void* Cout, const float* __restrict__ bias, const float* resid,
    int M, int N, int K)
{
  __shared__ __align__(16) char smem[16384];  // As(8K) + Bs(8K) | epilogue bounce (8.7K)
  bf16* As = (bf16*)smem;            // [128][32]
  bf16* Bs = (bf16*)(smem + 8192);   // [128][32]
  const int tid = threadIdx.x;
  const int wave = tid >> 6, lane = tid & 63;
  const int wm = wave >> 1, wn = wave & 1;

  const int npidn = gridDim.x, npidm = gridDim.y;
  const int pid = blockIdx.y * npidn + blockIdx.x;
  const int group_sz = 8 * npidn;
  const int gid = pid / group_sz;
  const int first_m = gid * 8;
  const int gsm = min(npidm - first_m, 8);
  const int pid_m = first_m + (pid % gsm);
  const int pid_n = (pid % group_sz) / gsm;
  const int m0 = pid_m * 128, n0 = pid_n * 128;

  const int r = lane & 15, qd = lane >> 4;
  const int srow = lane >> 2, scol = (lane & 3) * 8;

  f32x4 acc[4][4] = {};

  for (int k0 = 0; k0 < K; k0 += 32) {
#pragma unroll
    for (int t = 0; t < 2; ++t) {
      const int g = wave * 2 + t;
      if (AF32) {
        const float* A32 = (const float*)Ap;
        const float4 f0 = *(const float4*)(A32 + (size_t)(m0 + g * 16 + srow) * K + k0 + scol);
        const float4 f1 = *(const float4*)(A32 + (size_t)(m0 + g * 16 + srow) * K + k0 + scol + 4);
        bf16x8 v = { (__bf16)f0.x, (__bf16)f0.y, (__bf16)f0.z, (__bf16)f0.w,
                     (__bf16)f1.x, (__bf16)f1.y, (__bf16)f1.z, (__bf16)f1.w };
        *(bf16x8*)&As[g * 512 + lane * 8] = v;
      } else {
        const bf16* A16 = (const bf16*)Ap;
        GLDS16(A16 + (size_t)(m0 + g * 16 + srow) * K + k0 + scol, &As[g * 512]);
      }
      GLDS16(Bt + (size_t)(n0 + g * 16 + srow) * K + k0 + scol, &Bs[g * 512]);
    }
    __syncthreads();
    bf16x8 af[4], bfr[4];
#pragma unroll
    for (int i = 0; i < 4; ++i)
      af[i] = *(const bf16x8*)&As[(wm * 64 + i * 16 + r) * 32 + qd * 8];
#pragma unroll
    for (int j = 0; j < 4; ++j)
      bfr[j] = *(const bf16x8*)&Bs[(wn * 64 + j * 16 + r) * 32 + qd * 8];
#pragma unroll
    for (int i = 0; i < 4; ++i)
#pragma unroll
      for (int j = 0; j < 4; ++j)
        acc[i][j] = __builtin_amdgcn_mfma_f32_16x16x32_bf16(af[i], bfr[j], acc[i][j], 0, 0, 0);
    __syncthreads();
  }

  if (MODE == 0 || MODE == 1) {
    bf16* Wb = (bf16*)smem + wave * (16 * 68);
    const int rw = lane >> 2, c0 = (lane & 3) * 8;
#pragma unroll
    for (int i = 0; i < 4; ++i) {
#pragma unroll
      for (int j = 0; j < 4; ++j) {
        const int col = wn * 64 + j * 16 + r;
        const float bv = bias ? bias[n0 + col] : 0.f;
#pragma unroll
        for (int rr = 0; rr < 4; ++rr) {
          float v = acc[i][j][rr] + bv;
          if (MODE == 1) v = 0.5f * v * (1.f + erff(v * 0.70710678118654752f));
          Wb[(qd * 4 + rr) * 68 + j * 16 + r] = __float2bfloat16(v);
        }
      }
      asm volatile("s_waitcnt lgkmcnt(0)" ::: "memory");
      const int row_g = m0 + wm * 64 + i * 16 + rw;
      const bf16x8 v0 = *(const bf16x8*)&Wb[rw * 68 + c0];
      const bf16x8 v1 = *(const bf16x8*)&Wb[rw * 68 + 32 + c0];
      *(bf16x8*)((bf16*)Cout + (size_t)row_g * N + n0 + wn * 64 + c0)      = v0;
      *(bf16x8*)((bf16*)Cout + (size_t)row_g * N + n0 + wn * 64 + 32 + c0) = v1;
      asm volatile("" ::: "memory");
    }
  } else {
#pragma unroll
    for (int i = 0; i < 4; ++i) {
      const int row = m0 + wm * 64 + i * 16 + qd * 4;
#pragma unroll
      for (int j = 0; j < 4; ++j) {
        const int col = n0 + wn * 64 + j * 16 + r;
        const float bv = bias ? bias[col] : 0.f;
#pragma unroll
        for (int rr = 0; rr < 4; ++rr) {
          float v = acc[i][j][rr] + bv;
          const size_t idx = (size_t)(row + rr) * N + col;
          if (MODE == 2) ((float*)Cout)[idx] = v + resid[idx];
          else           ((float*)Cout)[idx] = v;
        }
      }
    }
  }
}

// ============ GEMM 256x256, 8-wave (2x4), BK=64, 8-phase counted-vmcnt pipeline ============
// Used ONLY for the cross-KV shape (M=32768: grid 1024 blocks = 4 clean CU rounds).
// Measured r5: 179 us vs 236 us on 128^2 (768 TF, MfmaUtil 32%, bank-conflict 0).
#define VM8 asm volatile("s_waitcnt vmcnt(8)" ::: "memory")
#define VM4 asm volatile("s_waitcnt vmcnt(4)" ::: "memory")
#define VM0 asm volatile("s_waitcnt vmcnt(0)" ::: "memory")
#define NOPST (void)0

#define PHASE256(BUF, KK, H, STAGE_STMT, WAIT_STMT) {                                   \
  bf16x8 af[4], bv[4];                                                                  \
  const int ab_ = ((BUF) * 2 + (KK)) * 8192;                                            \
  const int bb_ = 32768 + ((BUF) * 2 + (KK)) * 8192;                                    \
  _Pragma("unroll") for (int i2 = 0; i2 < 4; ++i2) {                                    \
    const int rl = wm * 128 + (H) * 64 + i2 * 16 + r;                                   \
    af[i2] = *(const bf16x8*)&sm[ab_ + rl * 32 + ((qd ^ ((rl >> 1) & 3)) << 3)];        \
  }                                                                                     \
  _Pragma("unroll") for (int j = 0; j < 4; ++j) {                                       \
    const int rl = wn * 64 + j * 16 + r;                                                \
    bv[j] = *(const bf16x8*)&sm[bb_ + rl * 32 + ((qd ^ ((rl >> 1) & 3)) << 3)];         \
  }                                                                                     \
  STAGE_STMT;                                                                           \
  __builtin_amdgcn_s_barrier();                                                         \
  asm volatile("s_waitcnt lgkmcnt(0)" ::: "memory");                                    \
  __builtin_amdgcn_sched_barrier(0);                                                    \
  __builtin_amdgcn_s_setprio(1);                                                        \
  _Pragma("unroll") for (int i2 = 0; i2 < 4; ++i2)                                      \
    _Pragma("unroll") for (int j = 0; j < 4; ++j)                                       \
      acc[(H) * 4 + i2][j] =                                                            \
          __builtin_amdgcn_mfma_f32_16x16x32_bf16(af[i2], bv[j], acc[(H) * 4 + i2][j],  \
                                                  0, 0, 0);                             \
  __builtin_amdgcn_s_setprio(0);                                                        \
  WAIT_STMT;                                                                            \
  __builtin_amdgcn_s_barrier();                                                         \
  __builtin_amdgcn_sched_barrier(0);                                                    \
}

template <int MODE>  // 0: bf16 (+bias opt); 1: bf16 gelu(+bias); 2: f32 + bias + resid
__global__ __launch_bounds__(512, 2) void gemm256_kernel(
    const bf16* __restrict__ A, const bf16* __restrict__ Bt,
    void* Cout, const float* __restrict__ bias, const float* __restrict__ resid,
    int M, int N, int K)
{
  __shared__ __align__(16) bf16 sm[65536];  // 128 KB
  const int tid = threadIdx.x;
  const int wave = tid >> 6, lane = tid & 63;
  const int wm = wave >> 2, wn = wave & 3;  // 2 x 4 wave grid, per-wave C = 128x64
  const int r = lane & 15, qd = lane >> 4;

  const int nbn = N >> 8;
  const int nwg = (M >> 8) * nbn;
  int pid = blockIdx.x;
  if ((nwg & 7) == 0) pid = (pid & 7) * (nwg >> 3) + (pid >> 3);  // bijective XCD chunking
  const int m0 = (pid / nbn) << 8, n0 = (pid % nbn) << 8;

  const int srow = lane >> 2, ssl = lane & 3;
  auto stage = [&](const bf16* src, int row0, int kbase, int slab) {
    const int ra = wave * 32 + srow;
    GLDS16(src + (size_t)(row0 + ra) * K + kbase + ((ssl ^ ((ra >> 1) & 3)) << 3),
           &sm[slab + wave * 1024]);
    const int rb = ra + 16;
    GLDS16(src + (size_t)(row0 + rb) * K + kbase + ((ssl ^ ((rb >> 1) & 3)) << 3),
           &sm[slab + wave * 1024 + 512]);
  };
  auto AOF = [](int buf, int kk) { return (buf * 2 + kk) * 8192; };
  auto BOF = [](int buf, int kk) { return 32768 + (buf * 2 + kk) * 8192; };

  f32x4 acc[8][4] = {};

  stage(A,  m0, 0,  AOF(0, 0));
  stage(Bt, n0, 0,  BOF(0, 0));
  stage(A,  m0, 32, AOF(0, 1));
  stage(Bt, n0, 32, BOF(0, 1));
  stage(A,  m0, 64, AOF(1, 0));
  stage(Bt, n0, 64, BOF(1, 0));
  VM8;
  __builtin_amdgcn_s_barrier();
  __builtin_amdgcn_sched_barrier(0);

  const int NT = K >> 6;
  int buf = 0;
  for (int t = 0; t + 2 < NT; ++t) {
    const int o = buf;
    PHASE256(o, 0, 0, stage(A,  m0, (t + 1) * 64 + 32, AOF(o ^ 1, 1)), NOPST);
    PHASE256(o, 0, 1, stage(Bt, n0, (t + 1) * 64 + 32, BOF(o ^ 1, 1)), VM8);
    PHASE256(o, 1, 0, stage(A,  m0, (t + 2) * 64,      AOF(o, 0)),     NOPST);
    PHASE256(o, 1, 1, stage(Bt, n0, (t + 2) * 64,      BOF(o, 0)),     VM8);
    buf ^= 1;
  }
  {  // tile NT-2
    const int o = buf, t = NT - 2;
    PHASE256(o, 0, 0, stage(A,  m0, (t + 1) * 64 + 32, AOF(o ^ 1, 1)), NOPST);
    PHASE256(o, 0, 1, stage(Bt, n0, (t + 1) * 64 + 32, BOF(o ^ 1, 1)), VM8);
    PHASE256(o, 1, 0, NOPST, NOPST);
    PHASE256(o, 1, 1, NOPST, VM4);
    buf ^= 1;
  }
  {  // tile NT-1 (drain)
    const int o = buf;
    PHASE256(o, 0, 0, NOPST, NOPST);
    PHASE256(o, 0, 1, NOPST, VM0);
    PHASE256(o, 1, 0, NOPST, NOPST);
    PHASE256(o, 1, 1, NOPST, NOPST);
  }

  if (MODE <= 1) {
    bf16* Wb = sm + wave * (16 * 68);
    const int rw = lane >> 2, c0 = (lane & 3) * 8;
#pragma unroll
    for (int i = 0; i < 8; ++i) {
#pragma unroll
      for (int j = 0; j < 4; ++j) {
        const int col = wn * 64 + j * 16 + r;
        const float bvs = bias ? bias[n0 + col] : 0.f;
#pragma unroll
        for (int rr = 0; rr < 4; ++rr) {
          float v = acc[i][j][rr] + bvs;
          if (MODE == 1) v = 0.5f * v * (1.f + erff(v * 0.70710678118654752f));
          Wb[(qd * 4 + rr) * 68 + j * 16 + r] = __float2bfloat16(v);
        }
      }
      asm volatile("s_waitcnt lgkmcnt(0)" ::: "memory");
      const int row_g = m0 + wm * 128 + i * 16 + rw;
      const bf16x8 v0 = *(const bf16x8*)&Wb[rw * 68 + c0];
      const bf16x8 v1 = *(const bf16x8*)&Wb[rw * 68 + 32 + c0];
      *(bf16x8*)((bf16*)Cout + (size_t)row_g * N + n0 + wn * 64 + c0)      = v0;
      *(bf16x8*)((bf16*)Cout + (size_t)row_g * N + n0 + wn * 64 + 32 + c0) = v1;
      asm volatile("" ::: "memory");
    }
  } else {
#pragma unroll
    for (int i = 0; i < 8; ++i) {
      const int row = m0 + wm * 128 + i * 16 + qd * 4;
#pragma unroll
      for (int j = 0; j < 4; ++j) {
        const int col = n0 + wn * 64 + j * 16 + r;
        const float bv = bias ? bias[col] : 0.f;
#pragma unroll
        for (int rr = 0; rr < 4; ++rr) {
          const size_t idx = (size_t)(row + rr) * N + col;
          ((float*)Cout)[idx] = acc[i][j][rr] + bv + (resid ? resid[idx] : 0.f);
        }
      }
    }
  }
}

// ---------------- fused attention (unchanged, proven) ----------------
__global__ __launch_bounds__(256) void attn_kernel(
    const bf16* __restrict__ Q, const bf16* __restrict__ Kg,
    const bf16* __restrict__ Vg, bf16* __restrict__ Out,
    int nk, int ldq, int ldkv)
{
  __shared__ __align__(16) bf16 Qs[128 * 64];
  __shared__ __align__(16) bf16 Ks[64 * 64];
  __shared__ __align__(16) bf16 Vt[64 * 64];
  __shared__ __align__(16) bf16 Ps[128 * 64];
  const int tid = threadIdx.x;
  const int wave = tid >> 6, lane = tid & 63;
  const int b = blockIdx.x >> 4, h = blockIdx.x & 15;
  const int r = lane & 15, qd = lane >> 4;
  const int srow = lane >> 3;
  const int scol = ((lane & 7) ^ srow) * 8;

#pragma unroll
  for (int t = 0; t < 4; ++t) {
    const int g = wave * 4 + t;
    GLDS16(Q + (size_t)(b * SQ_ + g * 8 + srow) * ldq + h * DH_ + scol, &Qs[g * 512]);
  }

  float mrow[2][4], lrow[2][4];
  f32x4 Oacc[2][4] = {};
#pragma unroll
  for (int i = 0; i < 2; ++i)
#pragma unroll
    for (int rr = 0; rr < 4; ++rr) { mrow[i][rr] = -1e30f; lrow[i][rr] = 0.f; }

  for (int kt = 0; kt < nk; kt += 64) {
#pragma unroll
    for (int t = 0; t < 2; ++t) {
      const int g = wave * 2 + t;
      GLDS16(Kg + (size_t)(b * nk + kt + g * 8 + srow) * ldkv + h * DH_ + scol, &Ks[g * 512]);
    }
#pragma unroll
    for (int c = 0; c < 2; ++c) {
      const int chunk = c * 256 + tid;
      const int key = chunk >> 3, d0 = (chunk & 7) * 8;
      const uint4 pv = *(const uint4*)(Vg + (size_t)(b * nk + kt + key) * ldkv + h * DH_ + d0);
      const unsigned short* pu = (const unsigned short*)&pv;
      const int s0 = key >> 3, k7 = key & 7;
#pragma unroll
      for (int t2 = 0; t2 < 8; ++t2) {
        const int row = d0 + t2;
        ((unsigned short*)Vt)[row * 64 + ((s0 ^ (row & 7)) << 3) + k7] = pu[t2];
      }
    }
    __syncthreads();

    f32x4 S[2][4] = {};
#pragma unroll
    for (int ks = 0; ks < 2; ++ks) {
      const int sl = ((ks * 4 + qd) ^ (r & 7)) * 8;
      bf16x8 aq[2], bk[4];
#pragma unroll
      for (int i = 0; i < 2; ++i)
        aq[i] = *(const bf16x8*)&Qs[(wave * 32 + i * 16 + r) * 64 + sl];
#pragma unroll
      for (int j = 0; j < 4; ++j)
        bk[j] = *(const bf16x8*)&Ks[(j * 16 + r) * 64 + sl];
#pragma unroll
      for (int i = 0; i < 2; ++i)
#pragma unroll
        for (int j = 0; j < 4; ++j)
          S[i][j] = __builtin_amdgcn_mfma_f32_16x16x32_bf16(aq[i], bk[j], S[i][j], 0, 0, 0);
    }

#pragma unroll
    for (int i = 0; i < 2; ++i) {
#pragma unroll
      for (int rr = 0; rr < 4; ++rr) {
        float mx = fmaxf(fmaxf(S[i][0][rr], S[i][1][rr]), fmaxf(S[i][2][rr], S[i][3][rr]));
#pragma unroll
        for (int mm = 1; mm < 16; mm <<= 1) mx = fmaxf(mx, __shfl_xor(mx, mm, 64));
        const float mnew = fmaxf(mrow[i][rr], mx);
        const float alpha = __expf(mrow[i][rr] - mnew);
        mrow[i][rr] = mnew;
        const int prow = wave * 32 + i * 16 + qd * 4 + rr;
        const int pr7 = prow & 7;
        float rs = 0.f;
#pragma unroll
        for (int j = 0; j < 4; ++j) {
          const float p = __expf(S[i][j][rr] - mnew);
          rs += p;
          Ps[prow * 64 + (((j * 2 + (r >> 3)) ^ pr7) << 3) + (r & 7)] = __float2bfloat16(p);
        }
#pragma unroll
        for (int mm = 1; mm < 16; mm <<= 1) rs += __shfl_xor(rs, mm, 64);
        lrow[i][rr] = lrow[i][rr] * alpha + rs;
#pragma unroll
        for (int jd = 0; jd < 4; ++jd) Oacc[i][jd][rr] *= alpha;
      }
    }
    __syncthreads();

#pragma unroll
    for (int ks = 0; ks < 2; ++ks) {
      const int sl = ((ks * 4 + qd) ^ (r & 7)) * 8;
      bf16x8 ap[2], bv[4];
#pragma unroll
      for (int i = 0; i < 2; ++i)
        ap[i] = *(const bf16x8*)&Ps[(wave * 32 + i * 16 + r) * 64 + sl];
#pragma unroll
      for (int jd = 0; jd < 4; ++jd)
        bv[jd] = *(const bf16x8*)&Vt[(jd * 16 + r) * 64 + sl];
#pragma unroll
      for (int i = 0; i < 2; ++i)
#pragma unroll
        for (int jd = 0; jd < 4; ++jd)
          Oacc[i][jd] = __builtin_amdgcn_mfma_f32_16x16x32_bf16(ap[i], bv[jd], Oacc[i][jd], 0, 0, 0);
    }
    __syncthreads();
  }

#pragma unroll
  for (int i = 0; i < 2; ++i) {
    const int rowl = wave * 32 + i * 16 + qd * 4;
#pragma unroll
    for (int jd = 0; jd < 4; ++jd) {
      const int col = h * DH_ + jd * 16 + r;
#pragma unroll
      for (int rr = 0; rr < 4; ++rr)
        Out[(size_t)(b * SQ_ + rowl + rr) * D_ + col] =
            __float2bfloat16(Oacc[i][jd][rr] / lrow[i][rr]);
    }
  }
}

extern "C" void kernel_launch(void* const* d_in, const int* in_sizes, int n_in,
                              void* d_out, int out_size, void* d_ws, size_t ws_size,
                              hipStream_t stream)
{
  (void)in_sizes; (void)n_in; (void)out_size;
  const float* x_in         = (const float*)d_in[0];
  const float* ctx          = (const float*)d_in[1];
  const float* attn_norm_w  = (const float*)d_in[3];
  const float* Wq           = (const float*)d_in[4];
  const float* Wk           = (const float*)d_in[5];
  const float* Wv           = (const float*)d_in[6];
  const float* Wo           = (const float*)d_in[7];
  const float* bo           = (const float*)d_in[8];
  const float* cross_norm_w = (const float*)d_in[9];
  const float* cWq          = (const float*)d_in[10];
  const float* cWk          = (const float*)d_in[11];
  const float* cWv          = (const float*)d_in[12];
  const float* cWo          = (const float*)d_in[13];
  const float* cbo          = (const float*)d_in[14];
  const float* ff_norm_w    = (const float*)d_in[15];
  const float* ff_w1        = (const float*)d_in[16];
  const float* ff_b1        = (const float*)d_in[17];
  const float* ff_w2        = (const float*)d_in[18];
  const float* ff_b2        = (const float*)d_in[19];
  const float* norm_out_w   = (const float*)d_in[20];
  const float* proj_w       = (const float*)d_in[21];
  const float* proj_b       = (const float*)d_in[22];

  char* ws = (char*)d_ws;
  size_t off = 0;
  auto carve = [&](size_t bytes) -> void* {
    void* p = ws + off;
    off += (bytes + 255) & ~(size_t)255;
    return p;
  };
  const size_t DD = (size_t)D_ * D_;
  bf16*  Wt  = (bf16*)carve((size_t)FF_ * D_ * 2);
  float* xf  = (float*)carve((size_t)MTOK * D_ * 4);
  bf16*  hb  = (bf16*)carve((size_t)MTOK * D_ * 2);
  bf16*  ao  = hb;
  char*  big = (char*)carve((size_t)144 * 1024 * 1024);
  bf16*  qkvb = (bf16*)big;
  bf16*  qb   = (bf16*)big;
  bf16*  kvb  = (bf16*)(big + (size_t)16 * 1024 * 1024);
  bf16*  gbuf = (bf16*)big;
  bf16*  ctxb = (bf16*)carve((size_t)MCTX * D_ * 2);
  const bool ctx16 = (ws_size >= off);

  auto T = [&](const float* src, bf16* dst, int R, int C, float scale = 1.0f) {
    transpose_kernel<<<dim3(C / 32, R / 32), 256, 0, stream>>>(src, dst, R, C, scale);
  };
  // 128^2 kernel wrappers (all M=8192 shapes + N=1024 shapes)
  auto G0 = [&](const bf16* A, bf16* C, int M, int N, int K) {
    gemm_bt_kernel<0, 0><<<dim3(N / 128, M / 128), 256, 0, stream>>>(
        (const void*)A, Wt, (void*)C, nullptr, nullptr, M, N, K);
  };
  auto G0f = [&](const float* A, bf16* C, int M, int N, int K) {
    gemm_bt_kernel<0, 1><<<dim3(N / 128, M / 128), 256, 0, stream>>>(
        (const void*)A, Wt, (void*)C, nullptr, nullptr, M, N, K);
  };
  auto G1 = [&](const bf16* A, bf16* C, const float* bias, int M, int N, int K) {
    gemm_bt_kernel<1, 0><<<dim3(N / 128, M / 128), 256, 0, stream>>>(
        (const void*)A, Wt, (void*)C, bias, nullptr, M, N, K);
  };
  auto G2 = [&](const bf16* A, const float* bias, const float* resid, int M, int N, int K) {
    gemm_bt_kernel<2, 0><<<dim3(N / 128, M / 128), 256, 0, stream>>>(
        (const void*)A, Wt, (void*)xf, bias, resid, M, N, K);
  };
  auto G3 = [&](const bf16* A, float* C, const float* bias, int M, int N, int K) {
    gemm_bt_kernel<3, 0><<<dim3(N / 128, M / 128), 256, 0, stream>>>(
        (const void*)A, Wt, (void*)C, bias, nullptr, M, N, K);
  };
  // 256^2 8-phase kernel (cross-KV only: M=32768 -> 1024-block grid)
  auto H0 = [&](const bf16* A, bf16* C, int M, int N, int K) {
    gemm256_kernel<0><<<dim3((M / 256) * (N / 256)), 512, 0, stream>>>(
        A, Wt, (void*)C, nullptr, nullptr, M, N, K);
  };

  if (ctx16)
    convert_kernel<<<(MCTX * D_) / (256 * 8), 256, 0, stream>>>(ctx, ctxb);

  for (int l = 0; l < L_; ++l) {
    const size_t o1 = (size_t)l * DD;
    const size_t o4 = (size_t)l * D_ * FF_;
    const float* res0 = (l == 0) ? x_in : xf;
    // ---- self-attention (fused QKV GEMM, N=3072; DH^-0.5 folded into Wq) ----
    rmsnorm_kernel<<<MTOK, 256, 0, stream>>>(res0, attn_norm_w + l * D_, hb);
    T(Wq + o1, Wt,          D_, D_, 0.125f);
    T(Wk + o1, Wt + DD,     D_, D_);
    T(Wv + o1, Wt + 2 * DD, D_, D_);
    G0(hb, qkvb, MTOK, 3 * D_, D_);
    rope_kernel<<<MTOK, 256, 0, stream>>>(qkvb,      SQ_ - 1, 3 * D_);
    rope_kernel<<<MTOK, 256, 0, stream>>>(qkvb + D_, SQ_ - 1, 3 * D_);
    attn_kernel<<<B_ * NH_, 256, 0, stream>>>(qkvb, qkvb + D_, qkvb + 2 * D_, ao,
                                              SQ_, 3 * D_, 3 * D_);
    T(Wo + o1, Wt, D_, D_);
    G2(ao, bo + l * D_, res0, MTOK, D_, D_);
    // ---- cross-attention (fused KV GEMM from bf16 context, N=2048) ----
    rmsnorm_kernel<<<MTOK, 256, 0, stream>>>(xf, cross_norm_w + l * D_, hb);
    T(cWq + o1, Wt, D_, D_, 0.125f);
    G0(hb, qb, MTOK, D_, D_);
    T(cWk + o1, Wt,      D_, D_);
    T(cWv + o1, Wt + DD, D_, D_);
    if (ctx16) H0(ctxb, kvb, MCTX, 2 * D_, D_);
    else       G0f(ctx, kvb, MCTX, 2 * D_, D_);
    rope_kernel<<<MTOK, 256, 0, stream>>>(qb,  SQ_ - 1, D_);
    rope_kernel<<<MCTX, 256, 0, stream>>>(kvb, SK_ - 1, 2 * D_);
    attn_kernel<<<B_ * NH_, 256, 0, stream>>>(qb, kvb, kvb + D_, ao, SK_, D_, 2 * D_);
    T(cWo + o1, Wt, D_, D_);
    G2(ao, cbo + l * D_, xf, MTOK, D_, D_);
    // ---- FFN (128^2 kernels: better grid fill for M=8192) ----
    rmsnorm_kernel<<<MTOK, 256, 0, stream>>>(xf, ff_norm_w + l * D_, hb);
    T(ff_w1 + o4, Wt, D_, FF_);
    G1(hb, gbuf, ff_b1 + l * FF_, MTOK, FF_, D_);
    T(ff_w2 + o4, Wt, FF_, D_);
    G2(gbuf, ff_b2 + l * D_, xf, MTOK, D_, FF_);
  }
  rmsnorm_kernel<<<MTOK, 256, 0, stream>>>(xf, norm_out_w, hb);
  T(proj_w, Wt, D_, D_);
  G3(hb, (float*)d_out, proj_b, MTOK, D_, D_);
}